// Round 7
// 425.599 us; speedup vs baseline: 1.0063x; 1.0063x over previous
//
#include <hip/hip_runtime.h>
#include <stdint.h>

#define T_STEPS 512
#define CELLS   4096            // 64*64
#define EPB     32              // envs per block (1 per lane, wave0 mirrored x2)
#define WPE     256             // packed world words per env (16 cells/word)
#define WPAD    257             // world LDS stride; word 256 = OOB sentinel (0)
#define ASTRIDE 132             // delta LDS stride: 128 words + pad (16B mult)
#define CHUNK   16              // steps per chunk (double-buffered flush)
#define NCHUNK  (T_STEPS / CHUNK)   // 32
#define KPC     (CHUNK / 4)         // 4 four-step k-iters per chunk
#define TSTR    18              // packed traj stride: 16 words + 2 (even)

// code: 2 = goal (g==10, priority), 1 = wall (w==1 && !goal), 0 = free
__device__ __forceinline__ uint32_t code4(float4 w, float4 g) {
    uint32_t b0 = (g.x == 10.0f) ? 2u : ((w.x == 1.0f) ? 1u : 0u);
    uint32_t b1 = (g.y == 10.0f) ? 2u : ((w.y == 1.0f) ? 1u : 0u);
    uint32_t b2 = (g.z == 10.0f) ? 2u : ((w.z == 1.0f) ? 1u : 0u);
    uint32_t b3 = (g.w == 10.0f) ? 2u : ((w.w == 1.0f) ? 1u : 0u);
    return b0 | (b1 << 2) | (b2 << 4) | (b3 << 6);   // 4 cells x 2 bits
}

// action -> flat delta e = dr*64 + dc, stored as int8
__device__ __forceinline__ int actdelta(int a) {
    return (a == 1) ? -64 : ((a == 2) ? 64 : ((a == 3) ? -1 : ((a == 4) ? 1 : 0)));
}

// ---- Fused kernel: pack world -> LDS + producer/consumer rollout ----
// staging (128 thr): raw world floats -> 2-bit codes directly in LDS (no
//                    global intermediate, no second dispatch, no device barrier)
// wave 0: rollout (env = tid&31, mirrored x2), writes 1 packed word/step
// wave 1: t=0 outputs (during chunk 0), then unpacks + flushes previous
//         chunk to global (coalesced), off the producer's dependence chain
__global__ __launch_bounds__(128) void rollout_fused(
    const float* __restrict__ s0,
    const int*   __restrict__ act,
    const float* __restrict__ world,
    float* __restrict__ out,
    int B)
{
    __shared__ uint32_t wlds[EPB * WPAD];        // 32896 B: 2-bit worlds
    __shared__ uint32_t alds[EPB * ASTRIDE];     // 16896 B: int8 step deltas
    __shared__ uint32_t tbuf[2][EPB * TSTR];     //  4608 B: packed traj dbuf
                                                 // total 54400 B

    const int tid = threadIdx.x;
    const int b0  = blockIdx.x * EPB;

    // ---- staging, 128 threads ----
    {   // world: 32 envs x 256 words; pack 16 cells (walls+goals) per word.
        // Per it: one env, 128 contiguous words = 8 KB contiguous walls span
        // (+8 KB goals); each lane covers its own 64 B via 4 float4 loads ->
        // every line fully consumed through L1. Same pattern as the old
        // pack_kernel, now writing straight to LDS.
        const float* wb0 = world + (size_t)b0 * (2 * CELLS);
        #pragma unroll 4
        for (int it = 0; it < 64; ++it) {
            const int idx = it * 128 + tid;     // word id within block
            const int env = idx >> 8;           // 0..31
            const int w   = idx & 255;          // 0..255
            const float* wb = wb0 + (size_t)env * (2 * CELLS) + w * 16;
            const float* gb = wb + CELLS;
            uint32_t word = 0;
            #pragma unroll
            for (int j = 0; j < 4; ++j) {
                const float4 wf = *(const float4*)(wb + 4 * j);
                const float4 gf = *(const float4*)(gb + 4 * j);
                word |= code4(wf, gf) << (8 * j);
            }
            wlds[env * WPAD + w] = word;
        }
    }
    if (tid < EPB) wlds[tid * WPAD + WPE] = 0u;   // OOB sentinel word = free
    {   // actions -> int8 deltas: 4096 words (128 per env)
        #pragma unroll 4
        for (int it = 0; it < 32; ++it) {
            const int widx = it * 128 + tid;
            const int env  = widx >> 7;
            const int w    = widx & 127;
            const int4 x = *(const int4*)(act + (size_t)(b0 + env) * T_STEPS + w * 4);
            const uint32_t dw = (uint32_t)(actdelta(x.x) & 255)
                              | ((uint32_t)(actdelta(x.y) & 255) << 8)
                              | ((uint32_t)(actdelta(x.z) & 255) << 16)
                              | ((uint32_t)(actdelta(x.w) & 255) << 24);
            alds[env * ASTRIDE + w] = dw;
        }
    }
    __syncthreads();

    float* const s_base = out;                                    // [B][513][2]
    float* const r_base = out + (size_t)B * (2 * (T_STEPS + 1));  // [B][513]

    if (tid >= 64 && tid < 64 + EPB) {   // t=0 outputs: flusher wave (idle in chunk 0)
        const int ee = tid - 64;
        const float2 si = *(const float2*)(s0 + 2 * (size_t)(b0 + ee));
        *(float2*)(s_base + (size_t)(b0 + ee) * (2 * (T_STEPS + 1))) = si;
        r_base[(size_t)(b0 + ee) * (T_STEPS + 1)] = 0.0f;
    }

    // rollout state (wave 0 only; harmless for wave 1)
    const int e = tid & (EPB - 1);
    const float2 s = *(const float2*)(s0 + 2 * (size_t)(b0 + e));
    int c = (int)s.y;
    int p = ((int)s.x) * 64 + c;            // invariant: p == r*64 + c (exact)
    const uint32_t* myw = wlds + e * WPAD;
    const uint32_t* myd = alds + e * ASTRIDE;
    const int ft = tid - 64;                // flusher lane id

    // semantics (verified R3-R13, absmax 0): idx in [-4096,-1] wraps (+4096,
    // single NumPy normalization); all other OOB -> fill(NaN) -> free cell.
    auto waddr = [](int q) -> int {
        const int w = (int)((((unsigned)q) >> 4) & 255u);   // (q & 4095) >> 4
        return ((unsigned)(q + CELLS) < 2u * CELLS) ? w : WPE;
    };

    for (int chunk = 0; chunk < NCHUNK; ++chunk) {
        if (tid < 64) {
            // ---- producer: 16 steps into tbuf[chunk&1], packed ----
            uint32_t* tb = &tbuf[chunk & 1][e * TSTR];
            const uint4 awv = *(const uint4*)(myd + chunk * 4);  // 16 steps, 1 wait
            const uint32_t aws[4] = {awv.x, awv.y, awv.z, awv.w};
            #pragma unroll
            for (int k = 0; k < KPC; ++k) {
                const uint32_t aw = aws[k];
                const int e0 = (int)(aw << 24) >> 24;
                const int e1 = (int)(aw << 16) >> 24;
                const int e2 = (int)(aw << 8) >> 24;
                const int e3 = (int)aw >> 24;
                const int es[4] = {e0, e1, e2, e3};
                #pragma unroll
                for (int jj = 0; jj < 2; ++jj) {    // two 2-step spec rounds
                    const int ls = k * 4 + jj * 2;  // local step in chunk
                    const int ea = es[2 * jj];
                    const int eb = es[2 * jj + 1];
                    const int dca = ea * (ea & 1);  // col part: ±1 -> ±1 else 0
                    const int dcb = eb * (eb & 1);
                    const int q0  = p + ea;
                    const int q10 = p + eb;
                    const int q11 = q0 + eb;
                    const uint32_t w0  = myw[waddr(q0)];
                    const uint32_t w10 = myw[waddr(q10)];
                    const uint32_t w11 = myw[waddr(q11)];
                    // resolve step t (identical to verified R8/R10/R11 logic)
                    const int l0 = (int)((w0 >> ((q0 & 15) << 1)) & 3);
                    const bool hw0 = (l0 == 1);
                    const int p0 = hw0 ? p : q0;
                    const int c0 = hw0 ? c : c + dca;
                    // resolve step t+1 from matching speculative read
                    const uint32_t W1 = hw0 ? w10 : w11;
                    const int q1 = p0 + eb;
                    const int l1 = (int)((W1 >> ((q1 & 15) << 1)) & 3);
                    const bool hw1 = (l1 == 1);
                    p = hw1 ? p0 : q1;
                    c = hw1 ? c0 : c0 + dcb;
                    // packed: bits[31:14]=p (18b signed), [13:2]=c (12b), [1:0]=cell
                    const uint32_t pk0 = ((uint32_t)p0 << 14)
                                       | (((uint32_t)c0 & 0xFFFu) << 2) | (uint32_t)l0;
                    const uint32_t pk1 = ((uint32_t)p << 14)
                                       | (((uint32_t)c & 0xFFFu) << 2) | (uint32_t)l1;
                    if (tid < 32)   // mirrored lanes skip: avoid same-addr serialization
                        *(uint2*)(&tb[ls]) = make_uint2(pk0, pk1);
                }
            }
        } else if (chunk > 0) {
            // ---- consumer: unpack + flush chunk-1 (coalesced) ----
            const int ch  = chunk - 1;
            const int buf = ch & 1;
            #pragma unroll 4
            for (int ee0 = 0; ee0 < EPB; ee0 += 2) {       // s: 32 floats/env
                const int ee = ee0 + (ft >> 5);
                const int j  = ft & 31;
                const uint32_t pk = tbuf[buf][ee * TSTR + (j >> 1)];
                const int pp = ((int)pk) >> 14;
                const int cc = ((int)(pk << 18)) >> 20;
                const float v = (j & 1) ? (float)cc : (float)((pp - cc) >> 6);
                s_base[(size_t)(b0 + ee) * (2 * (T_STEPS + 1)) + ch * 32 + 2 + j] = v;
            }
            #pragma unroll 4
            for (int ee0 = 0; ee0 < EPB; ee0 += 4) {       // r: 16 floats/env
                const int ee = ee0 + (ft >> 4);
                const int j  = ft & 15;
                const int v  = (int)(tbuf[buf][ee * TSTR + j] & 3u);
                const float rew = (v == 2) ? 1.0f : ((v == 1) ? -1.0f : -0.01f);
                r_base[(size_t)(b0 + ee) * (T_STEPS + 1) + ch * 16 + 1 + j] = rew;
            }
        }
        __syncthreads();
    }
    if (tid >= 64) {   // final flush: chunk NCHUNK-1
        const int ch  = NCHUNK - 1;
        const int buf = ch & 1;
        #pragma unroll 4
        for (int ee0 = 0; ee0 < EPB; ee0 += 2) {
            const int ee = ee0 + (ft >> 5);
            const int j  = ft & 31;
            const uint32_t pk = tbuf[buf][ee * TSTR + (j >> 1)];
            const int pp = ((int)pk) >> 14;
            const int cc = ((int)(pk << 18)) >> 20;
            const float v = (j & 1) ? (float)cc : (float)((pp - cc) >> 6);
            s_base[(size_t)(b0 + ee) * (2 * (T_STEPS + 1)) + ch * 32 + 2 + j] = v;
        }
        #pragma unroll 4
        for (int ee0 = 0; ee0 < EPB; ee0 += 4) {
            const int ee = ee0 + (ft >> 4);
            const int j  = ft & 15;
            const int v  = (int)(tbuf[buf][ee * TSTR + j] & 3u);
            const float rew = (v == 2) ? 1.0f : ((v == 1) ? -1.0f : -0.01f);
            r_base[(size_t)(b0 + ee) * (T_STEPS + 1) + ch * 16 + 1 + j] = rew;
        }
    }
}

extern "C" void kernel_launch(void* const* d_in, const int* in_sizes, int n_in,
                              void* d_out, int out_size, void* d_ws, size_t ws_size,
                              hipStream_t stream) {
    const float* s0    = (const float*)d_in[0];
    const int*   act   = (const int*)d_in[1];
    const float* world = (const float*)d_in[2];
    float*       out   = (float*)d_out;
    (void)d_ws; (void)ws_size;

    const int B = in_sizes[0] / 2;             // 8192

    rollout_fused<<<B / EPB, 128, 0, stream>>>(s0, act, world, out, B);
}

// Round 10
// 420.623 us; speedup vs baseline: 1.0182x; 1.0118x over previous
//
#include <hip/hip_runtime.h>
#include <stdint.h>

#define T_STEPS 512
#define CELLS   4096            // 64*64
#define EPB     32              // envs per block (1 per lane, wave0 mirrored x2)
#define WPE     256             // packed world words per env (16 cells/word)
#define WPAD    257             // world LDS stride; word 256 = OOB sentinel (0)
#define ASTRIDE 132             // delta LDS stride: 128 words + pad (16B mult)
#define CHUNK   16              // steps per chunk (double-buffered flush)
#define NCHUNK  (T_STEPS / CHUNK)   // 32
#define KPC     (CHUNK / 4)         // 4 four-step k-iters per chunk
#define TSTR    18              // packed traj stride: 16 words + 2 (even)
#define NTHR    256             // waves 0-1: producer/flusher (verified logic);
                                // waves 2-3: staging helpers, then barrier-spin

// code: 2 = goal (g==10, priority), 1 = wall (w==1 && !goal), 0 = free
__device__ __forceinline__ uint32_t code4(float4 w, float4 g) {
    uint32_t b0 = (g.x == 10.0f) ? 2u : ((w.x == 1.0f) ? 1u : 0u);
    uint32_t b1 = (g.y == 10.0f) ? 2u : ((w.y == 1.0f) ? 1u : 0u);
    uint32_t b2 = (g.z == 10.0f) ? 2u : ((w.z == 1.0f) ? 1u : 0u);
    uint32_t b3 = (g.w == 10.0f) ? 2u : ((w.w == 1.0f) ? 1u : 0u);
    return b0 | (b1 << 2) | (b2 << 4) | (b3 << 6);   // 4 cells x 2 bits
}

// action -> flat delta e = dr*64 + dc, stored as int8
__device__ __forceinline__ int actdelta(int a) {
    return (a == 1) ? -64 : ((a == 2) ? 64 : ((a == 3) ? -1 : ((a == 4) ? 1 : 0)));
}

// ---- Fused kernel: pack world -> LDS + producer/consumer rollout ----
// staging (256 thr = 4 waves): raw world floats -> 2-bit codes straight to LDS.
//   R7 post-mortem: at 128 thr the 1 MB/block world read ran on 2 waves/CU
//   (2 of 4 SIMDs idle) -> parallelism-starved. 4 waves cover all SIMDs.
// wave 0: rollout (env = tid&31, mirrored x2), writes 1 packed word/step
// wave 1: t=0 outputs (chunk 0), then unpacks + flushes previous chunk
// waves 2-3: staging only; spin through loop barriers (cheap s_barrier)
__global__ __launch_bounds__(NTHR) void rollout_fused(
    const float* __restrict__ s0,
    const int*   __restrict__ act,
    const float* __restrict__ world,
    float* __restrict__ out,
    int B)
{
    __shared__ uint32_t wlds[EPB * WPAD];        // 32896 B: 2-bit worlds
    __shared__ uint32_t alds[EPB * ASTRIDE];     // 16896 B: int8 step deltas
    __shared__ uint32_t tbuf[2][EPB * TSTR];     //  4608 B: packed traj dbuf
                                                 // total 54400 B

    const int tid = threadIdx.x;
    const int b0  = blockIdx.x * EPB;

    // ---- staging, 256 threads ----
    {   // world: 32 envs x 256 words; pack 16 cells (walls+goals) per word.
        // 8192 words / 256 thr = 32 iters; each lane does 8 float4 loads
        // (128 B) per iter; all four waves issue loads -> 4 SIMDs busy.
        const float* wb0 = world + (size_t)b0 * (2 * CELLS);
        #pragma unroll 4
        for (int it = 0; it < 32; ++it) {
            const int idx = it * NTHR + tid;    // word id within block
            const int env = idx >> 8;           // 0..31
            const int w   = idx & 255;          // 0..255
            const float* wb = wb0 + (size_t)env * (2 * CELLS) + w * 16;
            const float* gb = wb + CELLS;
            uint32_t word = 0;
            #pragma unroll
            for (int j = 0; j < 4; ++j) {
                const float4 wf = *(const float4*)(wb + 4 * j);
                const float4 gf = *(const float4*)(gb + 4 * j);
                word |= code4(wf, gf) << (8 * j);
            }
            wlds[env * WPAD + w] = word;
        }
    }
    if (tid < EPB) wlds[tid * WPAD + WPE] = 0u;   // OOB sentinel word = free
    {   // actions -> int8 deltas: 4096 words / 256 thr = 16 iters
        #pragma unroll 4
        for (int it = 0; it < 16; ++it) {
            const int widx = it * NTHR + tid;
            const int env  = widx >> 7;
            const int w    = widx & 127;
            const int4 x = *(const int4*)(act + (size_t)(b0 + env) * T_STEPS + w * 4);
            const uint32_t dw = (uint32_t)(actdelta(x.x) & 255)
                              | ((uint32_t)(actdelta(x.y) & 255) << 8)
                              | ((uint32_t)(actdelta(x.z) & 255) << 16)
                              | ((uint32_t)(actdelta(x.w) & 255) << 24);
            alds[env * ASTRIDE + w] = dw;
        }
    }
    __syncthreads();

    float* const s_base = out;                                    // [B][513][2]
    float* const r_base = out + (size_t)B * (2 * (T_STEPS + 1));  // [B][513]

    if (tid >= 64 && tid < 64 + EPB) {   // t=0 outputs: flusher wave (idle in chunk 0)
        const int ee = tid - 64;
        const float2 si = *(const float2*)(s0 + 2 * (size_t)(b0 + ee));
        *(float2*)(s_base + (size_t)(b0 + ee) * (2 * (T_STEPS + 1))) = si;
        r_base[(size_t)(b0 + ee) * (T_STEPS + 1)] = 0.0f;
    }

    // rollout state (wave 0 only; harmless for waves 1-3)
    const int e = tid & (EPB - 1);
    const float2 s = *(const float2*)(s0 + 2 * (size_t)(b0 + e));
    int c = (int)s.y;
    int p = ((int)s.x) * 64 + c;            // invariant: p == r*64 + c (exact)
    const uint32_t* myw = wlds + e * WPAD;
    const uint32_t* myd = alds + e * ASTRIDE;
    const int ft = tid - 64;                // flusher lane id (valid for wave 1)

    // semantics (verified R3-R13 + R7 fused, absmax 0): idx in [-4096,-1]
    // wraps (+4096, single NumPy normalization); other OOB -> free cell.
    auto waddr = [](int q) -> int {
        const int w = (int)((((unsigned)q) >> 4) & 255u);   // (q & 4095) >> 4
        return ((unsigned)(q + CELLS) < 2u * CELLS) ? w : WPE;
    };

    for (int chunk = 0; chunk < NCHUNK; ++chunk) {
        if (tid < 64) {
            // ---- producer: 16 steps into tbuf[chunk&1], packed ----
            uint32_t* tb = &tbuf[chunk & 1][e * TSTR];
            const uint4 awv = *(const uint4*)(myd + chunk * 4);  // 16 steps, 1 wait
            const uint32_t aws[4] = {awv.x, awv.y, awv.z, awv.w};
            #pragma unroll
            for (int k = 0; k < KPC; ++k) {
                const uint32_t aw = aws[k];
                const int e0 = (int)(aw << 24) >> 24;
                const int e1 = (int)(aw << 16) >> 24;
                const int e2 = (int)(aw << 8) >> 24;
                const int e3 = (int)aw >> 24;
                const int es[4] = {e0, e1, e2, e3};
                #pragma unroll
                for (int jj = 0; jj < 2; ++jj) {    // two 2-step spec rounds
                    const int ls = k * 4 + jj * 2;  // local step in chunk
                    const int ea = es[2 * jj];
                    const int eb = es[2 * jj + 1];
                    const int dca = ea * (ea & 1);  // col part: ±1 -> ±1 else 0
                    const int dcb = eb * (eb & 1);
                    const int q0  = p + ea;
                    const int q10 = p + eb;
                    const int q11 = q0 + eb;
                    const uint32_t w0  = myw[waddr(q0)];
                    const uint32_t w10 = myw[waddr(q10)];
                    const uint32_t w11 = myw[waddr(q11)];
                    // resolve step t (identical to verified R8/R10/R11 logic)
                    const int l0 = (int)((w0 >> ((q0 & 15) << 1)) & 3);
                    const bool hw0 = (l0 == 1);
                    const int p0 = hw0 ? p : q0;
                    const int c0 = hw0 ? c : c + dca;
                    // resolve step t+1 from matching speculative read
                    const uint32_t W1 = hw0 ? w10 : w11;
                    const int q1 = p0 + eb;
                    const int l1 = (int)((W1 >> ((q1 & 15) << 1)) & 3);
                    const bool hw1 = (l1 == 1);
                    p = hw1 ? p0 : q1;
                    c = hw1 ? c0 : c0 + dcb;
                    // packed: bits[31:14]=p (18b signed), [13:2]=c (12b), [1:0]=cell
                    const uint32_t pk0 = ((uint32_t)p0 << 14)
                                       | (((uint32_t)c0 & 0xFFFu) << 2) | (uint32_t)l0;
                    const uint32_t pk1 = ((uint32_t)p << 14)
                                       | (((uint32_t)c & 0xFFFu) << 2) | (uint32_t)l1;
                    if (tid < 32)   // mirrored lanes skip: avoid same-addr serialization
                        *(uint2*)(&tb[ls]) = make_uint2(pk0, pk1);
                }
            }
        } else if (tid < 128 && chunk > 0) {
            // ---- consumer (wave 1 only): unpack + flush chunk-1 ----
            const int ch  = chunk - 1;
            const int buf = ch & 1;
            #pragma unroll 4
            for (int ee0 = 0; ee0 < EPB; ee0 += 2) {       // s: 32 floats/env
                const int ee = ee0 + (ft >> 5);
                const int j  = ft & 31;
                const uint32_t pk = tbuf[buf][ee * TSTR + (j >> 1)];
                const int pp = ((int)pk) >> 14;
                const int cc = ((int)(pk << 18)) >> 20;
                const float v = (j & 1) ? (float)cc : (float)((pp - cc) >> 6);
                s_base[(size_t)(b0 + ee) * (2 * (T_STEPS + 1)) + ch * 32 + 2 + j] = v;
            }
            #pragma unroll 4
            for (int ee0 = 0; ee0 < EPB; ee0 += 4) {       // r: 16 floats/env
                const int ee = ee0 + (ft >> 4);
                const int j  = ft & 15;
                const int v  = (int)(tbuf[buf][ee * TSTR + j] & 3u);
                const float rew = (v == 2) ? 1.0f : ((v == 1) ? -1.0f : -0.01f);
                r_base[(size_t)(b0 + ee) * (T_STEPS + 1) + ch * 16 + 1 + j] = rew;
            }
        }
        // waves 2-3: staging helpers only — fall through to the barrier
        __syncthreads();
    }
    if (tid >= 64 && tid < 128) {   // final flush (wave 1): chunk NCHUNK-1
        const int ch  = NCHUNK - 1;
        const int buf = ch & 1;
        #pragma unroll 4
        for (int ee0 = 0; ee0 < EPB; ee0 += 2) {
            const int ee = ee0 + (ft >> 5);
            const int j  = ft & 31;
            const uint32_t pk = tbuf[buf][ee * TSTR + (j >> 1)];
            const int pp = ((int)pk) >> 14;
            const int cc = ((int)(pk << 18)) >> 20;
            const float v = (j & 1) ? (float)cc : (float)((pp - cc) >> 6);
            s_base[(size_t)(b0 + ee) * (2 * (T_STEPS + 1)) + ch * 32 + 2 + j] = v;
        }
        #pragma unroll 4
        for (int ee0 = 0; ee0 < EPB; ee0 += 4) {
            const int ee = ee0 + (ft >> 4);
            const int j  = ft & 15;
            const int v  = (int)(tbuf[buf][ee * TSTR + j] & 3u);
            const float rew = (v == 2) ? 1.0f : ((v == 1) ? -1.0f : -0.01f);
            r_base[(size_t)(b0 + ee) * (T_STEPS + 1) + ch * 16 + 1 + j] = rew;
        }
    }
}

extern "C" void kernel_launch(void* const* d_in, const int* in_sizes, int n_in,
                              void* d_out, int out_size, void* d_ws, size_t ws_size,
                              hipStream_t stream) {
    const float* s0    = (const float*)d_in[0];
    const int*   act   = (const int*)d_in[1];
    const float* world = (const float*)d_in[2];
    float*       out   = (float*)d_out;
    (void)d_ws; (void)ws_size;

    const int B = in_sizes[0] / 2;             // 8192

    rollout_fused<<<B / EPB, NTHR, 0, stream>>>(s0, act, world, out, B);
}